// Round 8
// baseline (368.988 us; speedup 1.0000x reference)
//
#include <hip/hip_runtime.h>
#include <math.h>

#define NNODES 100000
#define NEDGES 1600000
#define DIM 64
#define TAU 0.5f
#define EPSF 1e-12f
#define SEPS 1e-6f

#define K 256                           // buckets
#define RPB 391                         // rows per bucket (391*256 >= 100000)
#define TILE 8192                       // edges per k_bin block
#define CAP 7168                        // max records per bucket in k_sort LDS

typedef unsigned long long ull;
typedef unsigned short u16;

__device__ __forceinline__ float bf2f(u16 h) {
    return __uint_as_float((unsigned)h << 16);
}
__device__ __forceinline__ u16 f2bf(float f) {
    unsigned u = __float_as_uint(f);
    u += 0x7FFFu + ((u >> 16) & 1);  // round-to-nearest-even
    return (u16)(u >> 16);
}

// ---- pass 1: 256-bucket histogram of rows, LDS-privatized ----
__global__ __launch_bounds__(256) void k_bcount(const int* __restrict__ ei,
                                                int* __restrict__ bcnt, int E, int N) {
    __shared__ int cnt[K];
    cnt[threadIdx.x] = 0;
    __syncthreads();
    int stride = gridDim.x * blockDim.x;
    for (int e = blockIdx.x * blockDim.x + threadIdx.x; e < E; e += stride) {
        int r = min(max(ei[e], 0), N - 1);
        atomicAdd(&cnt[r / RPB], 1);
    }
    __syncthreads();
    int v = cnt[threadIdx.x];
    if (v) atomicAdd(&bcnt[threadIdx.x], v);
}

// ---- pass 2: scan bucket counts -> bbase[K+1]; init cursors; off[N]=E ----
__global__ __launch_bounds__(256) void k_bscan(const int* __restrict__ bcnt,
                                               int* __restrict__ bbase, int* __restrict__ bcur,
                                               int* __restrict__ off, int E, int N) {
    __shared__ int sc[K];
    int t = threadIdx.x;
    int v = bcnt[t];
    sc[t] = v;
    __syncthreads();
    for (int o = 1; o < K; o <<= 1) {
        int a = (t >= o) ? sc[t - o] : 0;
        __syncthreads();
        sc[t] += a;
        __syncthreads();
    }
    int ex = sc[t] - v;
    bbase[t] = ex;
    bcur[t] = ex;
    if (t == K - 1) { bbase[K] = sc[t]; off[N] = E; }
}

// ---- pass 3: LDS-staged binning. Records {w:32 | lrow:9 | col:17} appended to
//      bucket arenas in ~256B contiguous runs ----
__global__ __launch_bounds__(256) void k_bin(const int* __restrict__ ei, const float* __restrict__ w,
                                             int* __restrict__ bcur, ull* __restrict__ arena,
                                             int E, int N) {
    __shared__ ull stg[TILE];
    __shared__ int cnt[K], lscan[K], gbase[K], cur[K], sc[K];
    int t = threadIdx.x;
    int e0 = blockIdx.x * TILE;
    cnt[t] = 0; cur[t] = 0;
    __syncthreads();
    for (int i = t; i < TILE; i += 256) {
        int e = e0 + i;
        if (e < E) {
            int r = min(max(ei[e], 0), N - 1);
            atomicAdd(&cnt[r / RPB], 1);
        }
    }
    __syncthreads();
    int v = cnt[t];
    sc[t] = v;
    __syncthreads();
    for (int o = 1; o < K; o <<= 1) {
        int a = (t >= o) ? sc[t - o] : 0;
        __syncthreads();
        sc[t] += a;
        __syncthreads();
    }
    lscan[t] = sc[t] - v;
    if (v > 0) gbase[t] = atomicAdd(&bcur[t], v);  // one reservation per (block,bucket)
    __syncthreads();
    for (int i = t; i < TILE; i += 256) {
        int e = e0 + i;
        if (e < E) {
            int r = min(max(ei[e], 0), N - 1);
            int c = min(max(ei[E + e], 0), N - 1);
            int b = r / RPB, lr = r - b * RPB;
            int p = lscan[b] + atomicAdd(&cur[b], 1);
            stg[p] = ((ull)__float_as_uint(w[e]) << 32) | (unsigned)(c | (lr << 17));
        }
    }
    __syncthreads();
    // flush: thread t streams bucket t's records (sequential 8B runs, L2-merged)
    int nb = cnt[t];
    if (nb > 0) {
        int src = lscan[t];
        size_t dst = (size_t)gbase[t];
        for (int j = 0; j < nb; j++) arena[dst + j] = stg[src + j];
    }
}

// ---- pass 4: per-bucket counting sort (one block per bucket, all in LDS).
//      Computes deg per row -> invdeg[], off[], row-sorted {col, w} pairs. ----
__global__ __launch_bounds__(256) void k_sort(const int* __restrict__ bbase,
                                              ull* __restrict__ arena,
                                              float* __restrict__ invdeg,
                                              int* __restrict__ off, int N) {
    __shared__ ull stg[CAP];
    __shared__ int hist[RPB];
    __shared__ float degl[RPB];
    __shared__ int cur[RPB];
    __shared__ int sc[512];
    int t = threadIdx.x, b = blockIdx.x;
    int base = bbase[b];
    int cnt = min(bbase[b + 1] - base, CAP);
    for (int i = t; i < RPB; i += 256) { hist[i] = 0; degl[i] = 0.0f; cur[i] = 0; }
    __syncthreads();
    for (int i = t; i < cnt; i += 256) {
        ull rec = arena[base + i];
        stg[i] = rec;
        int lr = (int)((rec >> 17) & 0x1FF);
        atomicAdd(&hist[lr], 1);
        atomicAdd(&degl[lr], __uint_as_float((unsigned)(rec >> 32)));
    }
    __syncthreads();
    int v0 = (t < RPB) ? hist[t] : 0;
    int v1 = (t + 256 < RPB) ? hist[t + 256] : 0;
    sc[t] = v0; sc[t + 256] = v1;
    __syncthreads();
    for (int o = 1; o < 512; o <<= 1) {
        int a = (t >= o) ? sc[t - o] : 0;
        int c2 = (t + 256 >= o) ? sc[t + 256 - o] : 0;
        __syncthreads();
        sc[t] += a; sc[t + 256] += c2;
        __syncthreads();
    }
    int ex0 = sc[t] - v0, ex1 = sc[t + 256] - v1;
    hist[t] = ex0;
    if (t + 256 < RPB) hist[t + 256] = ex1;
    int rn0 = b * RPB + t;
    if (rn0 < N) { off[rn0] = base + ex0; invdeg[rn0] = 1.0f / fmaxf(degl[t], EPSF); }
    int rn1 = rn0 + 256;
    if (t + 256 < RPB && rn1 < N) { off[rn1] = base + ex1; invdeg[rn1] = 1.0f / fmaxf(degl[t + 256], EPSF); }
    __syncthreads();
    int2* out2 = (int2*)arena;
    for (int i = t; i < cnt; i += 256) {
        ull rec = stg[i];
        int lr = (int)((rec >> 17) & 0x1FF);
        int p = hist[lr] + atomicAdd(&cur[lr], 1);
        out2[base + p] = make_int2((int)(rec & 0x1FFFF), (int)(unsigned)(rec >> 32));
    }
}

// ---- max|kappa|: one thread per row over its CSR run ----
__global__ __launch_bounds__(256) void k_maxk(const int* __restrict__ off, const int2* __restrict__ csr,
                                              const float* __restrict__ invdeg,
                                              float* __restrict__ maxabs, int N) {
    int n = blockIdx.x * 256 + threadIdx.x;
    float m = 0.0f;
    if (n < N) {
        int s = off[n], e = off[n + 1];
        float a = 2.0f * invdeg[n] - 2.0f;
        for (int i = s; i < e; i++) {
            int2 pr = csr[i];
            m = fmaxf(m, fabsf(a + 2.0f * invdeg[pr.x]));
        }
    }
    for (int o = 32; o > 0; o >>= 1) m = fmaxf(m, __shfl_down(m, o, 64));
    __shared__ float red[4];
    int lane = threadIdx.x & 63, wid = threadIdx.x >> 6;
    if (lane == 0) red[wid] = m;
    __syncthreads();
    if (threadIdx.x == 0) {
        float bm = fmaxf(fmaxf(red[0], red[1]), fmaxf(red[2], red[3]));
        atomicMax((unsigned int*)maxabs, __float_as_uint(bm));
    }
}

// ---- per-node: row_sum / rho; rewrite csr in place as {col, w_norm}
//      (keeps ALL w_half math out of the bottleneck gather kernel) ----
__global__ void k_node(const int* __restrict__ off, const float* __restrict__ invdeg,
                       int2* __restrict__ csr, const float* __restrict__ maxabs,
                       float* __restrict__ rho, float* __restrict__ row_sum, int N) {
    int n = blockIdx.x * blockDim.x + threadIdx.x;
    if (n >= N) return;
    int s = off[n], e2 = off[n + 1];
    float dt = 0.5f / (*maxabs + 1e-6f);
    float a = 2.0f * invdeg[n] - 2.0f;
    float rs = 0.0f, ct = 0.0f, ks = 0.0f;
    for (int i = s; i < e2; i++) {
        int2 pr = csr[i];
        float we = __int_as_float(pr.y);
        float kap = a + 2.0f * invdeg[pr.x];
        float wh = fmaxf(we * (1.0f - 0.5f * dt * kap), 0.0f);
        if (wh > SEPS) { rs += wh; ct += 1.0f; ks += kap; }
    }
    float mk = ks / fmaxf(ct, 1.0f);
    rho[n] = 1.0f / (1.0f + expf(-mk));
    row_sum[n] = rs;
    float inv_rs = 1.0f / fmaxf(rs, EPSF);
    for (int i = s; i < e2; i++) {   // L1-hot second pass, sequential in-place rewrite
        int2 pr = csr[i];
        float we = __int_as_float(pr.y);
        float kap = a + 2.0f * invdeg[pr.x];
        float wh = fmaxf(we * (1.0f - 0.5f * dt * kap), 0.0f);
        if (wh <= SEPS) wh = 0.0f;
        csr[i] = make_int2(pr.x, __float_as_int(wh * inv_rs));
    }
}

// ---- hneigh = x@Wn^T (bf16, ws); out = rho*(x@Ws^T) + TAU*x ----
__global__ __launch_bounds__(256) void k_gemm(const float* __restrict__ x,
                                              const float* __restrict__ Wself,
                                              const float* __restrict__ Wneigh,
                                              const float* __restrict__ rho,
                                              u16* __restrict__ hneigh_h,
                                              float* __restrict__ out, int N) {
    __shared__ float xs[64 * 64];
    __shared__ float Wts[64 * 65];
    __shared__ float Wtn[64 * 65];
    int tid = threadIdx.x;
    for (int i = tid; i < 64 * 64; i += 256) {
        int d = i >> 6, k = i & 63;
        Wts[k * 65 + d] = Wself[i];
        Wtn[k * 65 + d] = Wneigh[i];
    }
    int n0 = blockIdx.x * 64;
    for (int i = tid; i < 64 * 64; i += 256) {
        int n = n0 + (i >> 6);
        xs[i] = (n < N) ? x[(size_t)n0 * 64 + i] : 0.0f;
    }
    __syncthreads();
    int d = tid & 63, ty = tid >> 6;
    float as[16], an[16];
#pragma unroll
    for (int j = 0; j < 16; j++) { as[j] = 0.0f; an[j] = 0.0f; }
    for (int k = 0; k < 64; k++) {
        float wsv = Wts[k * 65 + d];
        float wnv = Wtn[k * 65 + d];
#pragma unroll
        for (int j = 0; j < 16; j++) {
            float xv = xs[(ty + 4 * j) * 64 + k];
            as[j] = fmaf(xv, wsv, as[j]);
            an[j] = fmaf(xv, wnv, an[j]);
        }
    }
#pragma unroll
    for (int j = 0; j < 16; j++) {
        int nn = ty + 4 * j;
        int n = n0 + nn;
        if (n < N) {
            hneigh_h[(size_t)n * 64 + d] = f2bf(an[j]);
            out[(size_t)n * 64 + d] = rho[n] * as[j] + TAU * xs[nn * 64 + d];
        }
    }
}

// ---- neighbor aggregation: one wave per node, lane = dim; MINIMAL inner loop:
//      8B csr stream + one bf16 gather + one fmaf per edge; unroll x8 ----
__global__ __launch_bounds__(256) void k_aggr(const int* __restrict__ off,
                                              const int2* __restrict__ csr,
                                              const u16* __restrict__ hneigh_h,
                                              float* __restrict__ out, int N) {
    int lane = threadIdx.x & 63;
    int n = blockIdx.x * 4 + (threadIdx.x >> 6);
    if (n >= N) return;
    int s = off[n], end = off[n + 1];
    float acc = 0.0f;
    for (; s + 8 <= end; s += 8) {  // unroll x8: eight 128B gathers in flight
        int2 p0 = csr[s],     p1 = csr[s + 1], p2 = csr[s + 2], p3 = csr[s + 3];
        int2 p4 = csr[s + 4], p5 = csr[s + 5], p6 = csr[s + 6], p7 = csr[s + 7];
        float g0 = bf2f(hneigh_h[(size_t)p0.x * 64 + lane]);
        float g1 = bf2f(hneigh_h[(size_t)p1.x * 64 + lane]);
        float g2 = bf2f(hneigh_h[(size_t)p2.x * 64 + lane]);
        float g3 = bf2f(hneigh_h[(size_t)p3.x * 64 + lane]);
        float g4 = bf2f(hneigh_h[(size_t)p4.x * 64 + lane]);
        float g5 = bf2f(hneigh_h[(size_t)p5.x * 64 + lane]);
        float g6 = bf2f(hneigh_h[(size_t)p6.x * 64 + lane]);
        float g7 = bf2f(hneigh_h[(size_t)p7.x * 64 + lane]);
        acc = fmaf(__int_as_float(p0.y), g0, acc);
        acc = fmaf(__int_as_float(p1.y), g1, acc);
        acc = fmaf(__int_as_float(p2.y), g2, acc);
        acc = fmaf(__int_as_float(p3.y), g3, acc);
        acc = fmaf(__int_as_float(p4.y), g4, acc);
        acc = fmaf(__int_as_float(p5.y), g5, acc);
        acc = fmaf(__int_as_float(p6.y), g6, acc);
        acc = fmaf(__int_as_float(p7.y), g7, acc);
    }
    for (; s < end; s++) {
        int2 p0 = csr[s];
        acc = fmaf(__int_as_float(p0.y), bf2f(hneigh_h[(size_t)p0.x * 64 + lane]), acc);
    }
    out[(size_t)n * 64 + lane] += acc;  // unique owner, non-atomic RMW
}

// ---- final e-indexed pass: w_norm (coalesced) + edge_index->float, fused ----
__global__ void k_final(const int* __restrict__ ei, const float* __restrict__ w,
                        const float* __restrict__ invdeg, const float* __restrict__ row_sum,
                        const float* __restrict__ maxabs,
                        float* __restrict__ out_ei, float* __restrict__ out_wn, int E, int N) {
    int e = blockIdx.x * blockDim.x + threadIdx.x;
    if (e >= E) return;
    int r0 = ei[e], c0 = ei[E + e];
    int r = min(max(r0, 0), N - 1);
    int c = min(max(c0, 0), N - 1);
    float dt = 0.5f / (*maxabs + 1e-6f);
    float kap = 2.0f * invdeg[r] + 2.0f * invdeg[c] - 2.0f;
    float wh = fmaxf(w[e] * (1.0f - 0.5f * dt * kap), 0.0f);
    if (wh <= SEPS) wh = 0.0f;
    out_wn[e] = wh / fmaxf(row_sum[r], EPSF);
    out_ei[e] = (float)r0;
    out_ei[E + e] = (float)c0;
}

extern "C" void kernel_launch(void* const* d_in, const int* in_sizes, int n_in,
                              void* d_out, int out_size, void* d_ws, size_t ws_size,
                              hipStream_t stream) {
    (void)in_sizes; (void)n_in; (void)out_size; (void)ws_size;
    const int N = NNODES, E = NEDGES;

    const float* x      = (const float*)d_in[0];
    const int*   ei     = (const int*)d_in[1];
    const float* w      = (const float*)d_in[2];
    const float* Wself  = (const float*)d_in[3];
    const float* Wneigh = (const float*)d_in[4];

    float* out    = (float*)d_out;           // [N*64]
    float* out_ei = out + (size_t)N * DIM;   // [2E] edge_index as float (final)
    float* out_wn = out_ei + 2 * (size_t)E;  // [E]  w_norm (final)

    // CSR arena staged in out_ei region (dead until k_final overwrites it)
    ull*  arena = (ull*)out_ei;    // k_bin output: packed records
    int2* csr   = (int2*)out_ei;   // k_sort: {col, w_e} -> k_node: {col, w_norm}

    // ws layout:
    // invdeg f[N] | off i[N+1] | pad | rho f[N] | row_sum f[N] | maxabs f[4] |
    // bcnt i[256] | bbase i[257] | bcur i[256] | pad | hneigh_h u16[64N]  (~14.4 MB)
    float* invdeg  = (float*)d_ws;
    int*   off     = (int*)d_ws + (size_t)N;
    float* rho     = (float*)d_ws + 2 * (size_t)N + 16;
    float* row_sum = rho + (size_t)N;
    float* maxabs  = row_sum + (size_t)N;
    int*   bcnt    = (int*)(maxabs + 4);
    int*   bbase   = bcnt + 256;
    int*   bcur    = bbase + 257;
    u16*   hneigh_h = (u16*)((float*)d_ws + 4 * (size_t)N + 800);

    // zero maxabs + bcnt only; everything else fully overwritten
    hipMemsetAsync((void*)maxabs, 0, 260 * sizeof(float), stream);

    k_bcount<<<256, 256, 0, stream>>>(ei, bcnt, E, N);
    k_bscan<<<1, 256, 0, stream>>>(bcnt, bbase, bcur, off, E, N);
    k_bin<<<(E + TILE - 1) / TILE, 256, 0, stream>>>(ei, w, bcur, arena, E, N);
    k_sort<<<K, 256, 0, stream>>>(bbase, arena, invdeg, off, N);
    k_maxk<<<(N + 255) / 256, 256, 0, stream>>>(off, csr, invdeg, maxabs, N);
    k_node<<<(N + 255) / 256, 256, 0, stream>>>(off, invdeg, csr, maxabs, rho, row_sum, N);
    k_gemm<<<(N + 63) / 64, 256, 0, stream>>>(x, Wself, Wneigh, rho, hneigh_h, out, N);
    k_aggr<<<(N + 3) / 4, 256, 0, stream>>>(off, csr, hneigh_h, out, N);
    k_final<<<(E + 255) / 256, 256, 0, stream>>>(ei, w, invdeg, row_sum, maxabs,
                                                 out_ei, out_wn, E, N);
}